// Round 10
// baseline (660.473 us; speedup 1.0000x reference)
//
#include <hip/hip_runtime.h>
#include <math.h>

#define LDIM 4096
#define CDIM 1024
#define HDIM 16
#define KDIM 64
#define SDIM 33
#define HALF_SS 16
#define MAXF 16.0f
#define MINF 1.0f
#define MAXR 256.0f

// 0.5-ulp predictors for np's fp32 transcendentals: fp64 op, one round to fp32.
__device__ __forceinline__ float sigmoid_np(float z) {
  // 1/(1+exp(-z)) with exp via fp64; each fp32 materialization point kept fp32
  float e = (float)exp(-(double)z);
  return __fdiv_rn(1.0f, __fadd_rn(1.0f, e));
}
__device__ __forceinline__ float silu_f(float z) {  // jax.nn order: z * sigmoid(z)
  return __fmul_rn(z, sigmoid_np(z));
}

// numpy pairwise-8 sum (8 <= n <= 128 path)
__device__ __forceinline__ float np_pairwise_sum(const float* a, int n) {
  float r[8];
#pragma unroll
  for (int j = 0; j < 8; ++j) r[j] = a[j];
  int i = 8;
  for (; i + 8 <= n; i += 8)
#pragma unroll
    for (int j = 0; j < 8; ++j) r[j] = __fadd_rn(r[j], a[i + j]);
  float res = __fadd_rn(__fadd_rn(__fadd_rn(r[0], r[1]), __fadd_rn(r[2], r[3])),
                        __fadd_rn(__fadd_rn(r[4], r[5]), __fadd_rn(r[6], r[7])));
  for (; i < n; ++i) res = __fadd_rn(res, a[i]);
  return res;
}

// ------- Kernel A: wave projection — fp64 dot -> fp32 cast -> fp32 elementwise
__global__ __launch_bounds__(256) void wave_kernel(
    const float* __restrict__ x, const float* __restrict__ Ww,
    const float* __restrict__ bw, float* __restrict__ fa, float* __restrict__ pa) {
  __shared__ float xs[CDIM];
  __shared__ float wp[2 * HDIM];
  int l = blockIdx.x;
  int tid = threadIdx.x;
  const float* xrow = x + (size_t)l * CDIM;
  for (int c = tid; c < CDIM; c += 256) xs[c] = xrow[c];
  __syncthreads();
  if (tid < 2 * HDIM) {
    const float* wrow = Ww + tid * CDIM;
    double acc = 0.0;  // exact products of fp32 inputs; fp64 sum
    for (int c = 0; c < CDIM; ++c) acc += (double)xs[c] * (double)wrow[c];
    float v32 = (float)acc;          // single cast to fp32 (bias bw == 0)
    wp[tid] = silu_f(v32);           // fp32 silu
  }
  __syncthreads();
  if (tid == 0) {
    float fv[HDIM], pv[HDIM];
    for (int h = 0; h < HDIM; ++h) {
      fv[h] = __fadd_rn(__fmul_rn(sigmoid_np(wp[h]), MAXF - MINF), MINF);
      float t32 = (float)tanh((double)wp[HDIM + h]);
      pv[h] = __fmul_rn(t32, MAXF);
    }
    fa[l] = __fdiv_rn(np_pairwise_sum(fv, HDIM), (float)HDIM);
    pa[l] = __fdiv_rn(np_pairwise_sum(pv, HDIM), (float)HDIM);
  }
}

// --- GEMM: C = silu(fp32(A64 @ B64^T) ), fp64 accumulate, fp32 silu/store ----
template <bool HAS_BIAS>
__global__ __launch_bounds__(256) void gemm_bt_silu(
    const float* __restrict__ A, const float* __restrict__ B,
    const float* __restrict__ bias, float* __restrict__ Cout,
    int M, int N, int Kd) {
  __shared__ float As[16][64];
  __shared__ float Bs[16][64];
  int tid = threadIdx.x;
  int tx = tid & 15, ty = tid >> 4;
  int m0 = blockIdx.y * 64, n0 = blockIdx.x * 64;
  double acc[4][4] = {};
  for (int kt = 0; kt < Kd; kt += 16) {
    int m = tid >> 2;
    int kb = (tid & 3) * 4;
    float4 va = *(const float4*)(A + (size_t)(m0 + m) * Kd + kt + kb);
    As[kb + 0][m] = va.x; As[kb + 1][m] = va.y;
    As[kb + 2][m] = va.z; As[kb + 3][m] = va.w;
    float4 vb = *(const float4*)(B + (size_t)(n0 + m) * Kd + kt + kb);
    Bs[kb + 0][m] = vb.x; Bs[kb + 1][m] = vb.y;
    Bs[kb + 2][m] = vb.z; Bs[kb + 3][m] = vb.w;
    __syncthreads();
#pragma unroll
    for (int kk = 0; kk < 16; ++kk) {
      float4 a4 = *(const float4*)&As[kk][ty * 4];
      float4 b4 = *(const float4*)&Bs[kk][tx * 4];
      double a[4] = {(double)a4.x, (double)a4.y, (double)a4.z, (double)a4.w};
      double b[4] = {(double)b4.x, (double)b4.y, (double)b4.z, (double)b4.w};
#pragma unroll
      for (int i = 0; i < 4; ++i)
#pragma unroll
        for (int j2 = 0; j2 < 4; ++j2) acc[i][j2] += a[i] * b[j2];
    }
    __syncthreads();
  }
#pragma unroll
  for (int i = 0; i < 4; ++i) {
    int mm = m0 + ty * 4 + i;
#pragma unroll
    for (int j2 = 0; j2 < 4; ++j2) {
      int nn = n0 + tx * 4 + j2;
      float v32 = (float)acc[i][j2];  // fp64 dot -> one fp32 cast (bias == 0)
      if (HAS_BIAS) v32 = __fadd_rn(v32, bias[nn]);
      Cout[(size_t)mm * N + nn] = silu_f(v32);  // fp32 silu
    }
  }
}

// ---------------- Kernel C: R5 fp32 chain (geometry/interp/normalize/einsum) -
__global__ __launch_bounds__(256) void conv_kernel(
    const float* __restrict__ x, const float* __restrict__ km,
    const float* __restrict__ fa, const float* __restrict__ pa,
    float* __restrict__ conv) {
  int l = blockIdx.x;
  int tid = threadIdx.x;
  __shared__ int s_idx[SDIM];
  __shared__ int s_ifl[SDIM];
  __shared__ float s_wc[SDIM];
  __shared__ float s_val[SDIM];
  __shared__ float kern[HDIM][SDIM];
  __shared__ float s_den[HDIM];
  if (tid < SDIM) {
    float f = fa[l], p = pa[l];
    float rel = __fadd_rn(__fmul_rn((float)(tid - HALF_SS), f), p);
    float pos = __fadd_rn((float)l, rel);
    bool valid = (pos >= 0.f) && (pos < (float)LDIM);
    int idx = (int)pos;                       // trunc toward zero
    idx = min(max(idx, 0), LDIM - 1);
    s_idx[tid] = idx;
    s_val[tid] = valid ? 1.f : 0.f;
    float np_ = __fdiv_rn(__fadd_rn(rel, MAXR), 2.f * MAXR);  // /512 exact
    np_ = fminf(fmaxf(np_, 0.f), 1.f);
    float idxf = __fmul_rn(np_, (float)(KDIM - 1));
    int ifl = (int)idxf;
    ifl = min(max(ifl, 0), KDIM - 2);
    s_ifl[tid] = ifl;
    s_wc[tid] = __fsub_rn(idxf, (float)ifl);
  }
  __syncthreads();
  for (int t = tid; t < HDIM * SDIM; t += 256) {
    int h = t / SDIM, s = t - h * SDIM;
    const float* kb = km + (size_t)l * CDIM + h * KDIM;
    float wc = s_wc[s];
    float wf = __fsub_rn(1.f, wc);
    float v = __fadd_rn(__fmul_rn(kb[s_ifl[s]], wf), __fmul_rn(kb[s_ifl[s] + 1], wc));
    kern[h][s] = __fmul_rn(v, s_val[s]);
  }
  __syncthreads();
  if (tid < HDIM) {
    float sum = np_pairwise_sum(&kern[tid][0], SDIM);
    s_den[tid] = __fadd_rn(sum, 1e-8f);
  }
  __syncthreads();
  for (int t = tid; t < HDIM * SDIM; t += 256) {
    int h = t / SDIM, s = t - h * SDIM;
    kern[h][s] = __fdiv_rn(kern[h][s], s_den[h]);
  }
  __syncthreads();
  float acc[4] = {0.f, 0.f, 0.f, 0.f};
  for (int s = 0; s < SDIM; ++s) {
    const float* xr = x + (size_t)s_idx[s] * CDIM;
#pragma unroll
    for (int q = 0; q < 4; ++q) {
      int c = tid + q * 256;
      acc[q] = __fadd_rn(acc[q], __fmul_rn(xr[c], kern[c >> 6][s]));
    }
  }
#pragma unroll
  for (int q = 0; q < 4; ++q) {
    int c = tid + q * 256;
    conv[(size_t)l * CDIM + c] = acc[q];
  }
}

extern "C" void kernel_launch(void* const* d_in, const int* in_sizes, int n_in,
                              void* d_out, int out_size, void* d_ws, size_t ws_size,
                              hipStream_t stream) {
  const float* x  = (const float*)d_in[0];
  const float* Ww = (const float*)d_in[1];
  const float* bw = (const float*)d_in[2];
  const float* Wk = (const float*)d_in[3];
  const float* bk = (const float*)d_in[4];
  const float* Wo = (const float*)d_in[5];
  float* out = (float*)d_out;

  float* fa   = (float*)d_ws;
  float* pa   = fa + LDIM;
  float* km   = pa + LDIM;                   // 16 MB
  float* conv = km + (size_t)LDIM * CDIM;    // 16 MB

  wave_kernel<<<LDIM, 256, 0, stream>>>(x, Ww, bw, fa, pa);

  dim3 ggrid(CDIM / 64, LDIM / 64);
  gemm_bt_silu<true><<<ggrid, 256, 0, stream>>>(x, Wk, bk, km, LDIM, CDIM, CDIM);

  conv_kernel<<<LDIM, 256, 0, stream>>>(x, km, fa, pa, conv);

  gemm_bt_silu<false><<<ggrid, 256, 0, stream>>>(conv, Wo, nullptr, out, LDIM, CDIM, CDIM);
}

// Round 11
// 645.109 us; speedup vs baseline: 1.0238x; 1.0238x over previous
//
#include <hip/hip_runtime.h>
#include <math.h>

#define LDIM 4096
#define CDIM 1024
#define HDIM 16
#define KDIM 64
#define SDIM 33
#define HALF_SS 16
#define MAXF 16.0f
#define MINF 1.0f
#define MAXR 256.0f

// 0.5-ulp predictors for np's fp32 transcendentals: fp64 op, one round to fp32.
__device__ __forceinline__ float sigmoid_np(float z) {
  float e = (float)exp(-(double)z);
  return __fdiv_rn(1.0f, __fadd_rn(1.0f, e));
}
__device__ __forceinline__ float silu_f(float z) {  // jax.nn order: z * sigmoid(z)
  return __fmul_rn(z, sigmoid_np(z));
}

// numpy pairwise-8 sum (8 <= n <= 128 path)
__device__ __forceinline__ float np_pairwise_sum(const float* a, int n) {
  float r[8];
#pragma unroll
  for (int j = 0; j < 8; ++j) r[j] = a[j];
  int i = 8;
  for (; i + 8 <= n; i += 8)
#pragma unroll
    for (int j = 0; j < 8; ++j) r[j] = __fadd_rn(r[j], a[i + j]);
  float res = __fadd_rn(__fadd_rn(__fadd_rn(r[0], r[1]), __fadd_rn(r[2], r[3])),
                        __fadd_rn(__fadd_rn(r[4], r[5]), __fadd_rn(r[6], r[7])));
  for (; i < n; ++i) res = __fadd_rn(res, a[i]);
  return res;
}

// ------- Kernel A: wave projection — fp64 dot (8-lane split) -> fp32 cast ----
__global__ __launch_bounds__(256) void wave_kernel(
    const float* __restrict__ x, const float* __restrict__ Ww,
    const float* __restrict__ bw, float* __restrict__ fa, float* __restrict__ pa) {
  __shared__ float xs[CDIM];
  __shared__ float wp[2 * HDIM];
  int l = blockIdx.x;
  int tid = threadIdx.x;
  const float* xrow = x + (size_t)l * CDIM;
  for (int c = tid; c < CDIM; c += 256) xs[c] = xrow[c];
  __syncthreads();
  int j = tid >> 3, sub = tid & 7;  // 32 outputs x 8 lanes, fp64 partials
  const float* wrow = Ww + j * CDIM;
  double acc = 0.0;
  for (int c = sub; c < CDIM; c += 8) acc += (double)xs[c] * (double)wrow[c];
  for (int off = 4; off; off >>= 1) acc += __shfl_down(acc, off, 8);
  if (sub == 0) {
    float v32 = (float)(acc + (double)bw[j]);  // single cast to fp32 (bw == 0)
    wp[j] = silu_f(v32);
  }
  __syncthreads();
  if (tid == 0) {
    float fv[HDIM], pv[HDIM];
    for (int h = 0; h < HDIM; ++h) {
      fv[h] = __fadd_rn(__fmul_rn(sigmoid_np(wp[h]), MAXF - MINF), MINF);
      float t32 = (float)tanh((double)wp[HDIM + h]);
      pv[h] = __fmul_rn(t32, MAXF);
    }
    fa[l] = __fdiv_rn(np_pairwise_sum(fv, HDIM), (float)HDIM);
    pa[l] = __fdiv_rn(np_pairwise_sum(pv, HDIM), (float)HDIM);
  }
}

// --- GEMM: C = silu(fp32(A64 @ B64^T)); 128x64 tile, 8x4 fp64 acc/thread -----
// fp64 accumulate (order-insensitive at fp32-cast granularity), fp32 silu/store.
template <bool HAS_BIAS>
__global__ __launch_bounds__(256) void gemm_bt_silu(
    const float* __restrict__ A, const float* __restrict__ B,
    const float* __restrict__ bias, float* __restrict__ Cout,
    int M, int N, int Kd) {
  __shared__ float Asf[16][128];
  __shared__ float Bsf[16][64];
  int tid = threadIdx.x;
  int tx = tid & 15, ty = tid >> 4;      // tx: n-sub (4 cols), ty: m-sub (8 rows)
  int m0 = blockIdx.y * 128, n0 = blockIdx.x * 64;
  double acc[8][4] = {};
  for (int kt = 0; kt < Kd; kt += 16) {
    // stage A: 128 rows x 16 k = 512 float4, 2 per thread
#pragma unroll
    for (int q = 0; q < 2; ++q) {
      int e = tid + 256 * q;             // 0..511
      int row = e >> 2, kq = (e & 3) * 4;
      float4 va = *(const float4*)(A + (size_t)(m0 + row) * Kd + kt + kq);
      Asf[kq + 0][row] = va.x; Asf[kq + 1][row] = va.y;
      Asf[kq + 2][row] = va.z; Asf[kq + 3][row] = va.w;
    }
    // stage B: 64 rows x 16 k = 256 float4, 1 per thread
    {
      int row = tid >> 2, kq = (tid & 3) * 4;
      float4 vb = *(const float4*)(B + (size_t)(n0 + row) * Kd + kt + kq);
      Bsf[kq + 0][row] = vb.x; Bsf[kq + 1][row] = vb.y;
      Bsf[kq + 2][row] = vb.z; Bsf[kq + 3][row] = vb.w;
    }
    __syncthreads();
#pragma unroll
    for (int kk = 0; kk < 16; ++kk) {
      float4 a0 = *(const float4*)&Asf[kk][ty * 8];
      float4 a1 = *(const float4*)&Asf[kk][ty * 8 + 4];
      float4 b4 = *(const float4*)&Bsf[kk][tx * 4];
      double a[8] = {(double)a0.x, (double)a0.y, (double)a0.z, (double)a0.w,
                     (double)a1.x, (double)a1.y, (double)a1.z, (double)a1.w};
      double b[4] = {(double)b4.x, (double)b4.y, (double)b4.z, (double)b4.w};
#pragma unroll
      for (int i = 0; i < 8; ++i)
#pragma unroll
        for (int j2 = 0; j2 < 4; ++j2) acc[i][j2] += a[i] * b[j2];
    }
    __syncthreads();
  }
#pragma unroll
  for (int i = 0; i < 8; ++i) {
    int mm = m0 + ty * 8 + i;
#pragma unroll
    for (int j2 = 0; j2 < 4; ++j2) {
      int nn = n0 + tx * 4 + j2;
      float v32 = (float)acc[i][j2];     // fp64 dot -> one fp32 cast (bias == 0)
      if (HAS_BIAS) v32 = __fadd_rn(v32, bias[nn]);
      Cout[(size_t)mm * N + nn] = silu_f(v32);
    }
  }
}

// ---------------- Kernel C: R10 fp32 chain — byte-identical ------------------
__global__ __launch_bounds__(256) void conv_kernel(
    const float* __restrict__ x, const float* __restrict__ km,
    const float* __restrict__ fa, const float* __restrict__ pa,
    float* __restrict__ conv) {
  int l = blockIdx.x;
  int tid = threadIdx.x;
  __shared__ int s_idx[SDIM];
  __shared__ int s_ifl[SDIM];
  __shared__ float s_wc[SDIM];
  __shared__ float s_val[SDIM];
  __shared__ float kern[HDIM][SDIM];
  __shared__ float s_den[HDIM];
  if (tid < SDIM) {
    float f = fa[l], p = pa[l];
    float rel = __fadd_rn(__fmul_rn((float)(tid - HALF_SS), f), p);
    float pos = __fadd_rn((float)l, rel);
    bool valid = (pos >= 0.f) && (pos < (float)LDIM);
    int idx = (int)pos;                       // trunc toward zero
    idx = min(max(idx, 0), LDIM - 1);
    s_idx[tid] = idx;
    s_val[tid] = valid ? 1.f : 0.f;
    float np_ = __fdiv_rn(__fadd_rn(rel, MAXR), 2.f * MAXR);
    np_ = fminf(fmaxf(np_, 0.f), 1.f);
    float idxf = __fmul_rn(np_, (float)(KDIM - 1));
    int ifl = (int)idxf;
    ifl = min(max(ifl, 0), KDIM - 2);
    s_ifl[tid] = ifl;
    s_wc[tid] = __fsub_rn(idxf, (float)ifl);
  }
  __syncthreads();
  for (int t = tid; t < HDIM * SDIM; t += 256) {
    int h = t / SDIM, s = t - h * SDIM;
    const float* kb = km + (size_t)l * CDIM + h * KDIM;
    float wc = s_wc[s];
    float wf = __fsub_rn(1.f, wc);
    float v = __fadd_rn(__fmul_rn(kb[s_ifl[s]], wf), __fmul_rn(kb[s_ifl[s] + 1], wc));
    kern[h][s] = __fmul_rn(v, s_val[s]);
  }
  __syncthreads();
  if (tid < HDIM) {
    float sum = np_pairwise_sum(&kern[tid][0], SDIM);
    s_den[tid] = __fadd_rn(sum, 1e-8f);
  }
  __syncthreads();
  for (int t = tid; t < HDIM * SDIM; t += 256) {
    int h = t / SDIM, s = t - h * SDIM;
    kern[h][s] = __fdiv_rn(kern[h][s], s_den[h]);
  }
  __syncthreads();
  float acc[4] = {0.f, 0.f, 0.f, 0.f};
  for (int s = 0; s < SDIM; ++s) {
    const float* xr = x + (size_t)s_idx[s] * CDIM;
#pragma unroll
    for (int q = 0; q < 4; ++q) {
      int c = tid + q * 256;
      acc[q] = __fadd_rn(acc[q], __fmul_rn(xr[c], kern[c >> 6][s]));
    }
  }
#pragma unroll
  for (int q = 0; q < 4; ++q) {
    int c = tid + q * 256;
    conv[(size_t)l * CDIM + c] = acc[q];
  }
}

extern "C" void kernel_launch(void* const* d_in, const int* in_sizes, int n_in,
                              void* d_out, int out_size, void* d_ws, size_t ws_size,
                              hipStream_t stream) {
  const float* x  = (const float*)d_in[0];
  const float* Ww = (const float*)d_in[1];
  const float* bw = (const float*)d_in[2];
  const float* Wk = (const float*)d_in[3];
  const float* bk = (const float*)d_in[4];
  const float* Wo = (const float*)d_in[5];
  float* out = (float*)d_out;

  float* fa   = (float*)d_ws;
  float* pa   = fa + LDIM;
  float* km   = pa + LDIM;                   // 16 MB
  float* conv = km + (size_t)LDIM * CDIM;    // 16 MB

  wave_kernel<<<LDIM, 256, 0, stream>>>(x, Ww, bw, fa, pa);

  dim3 ggrid(CDIM / 64, LDIM / 128);         // 16 x 32 = 512 blocks
  gemm_bt_silu<true><<<ggrid, 256, 0, stream>>>(x, Wk, bk, km, LDIM, CDIM, CDIM);

  conv_kernel<<<LDIM, 256, 0, stream>>>(x, km, fa, pa, conv);

  gemm_bt_silu<false><<<ggrid, 256, 0, stream>>>(conv, Wo, nullptr, out, LDIM, CDIM, CDIM);
}

// Round 12
// 539.777 us; speedup vs baseline: 1.2236x; 1.1951x over previous
//
#include <hip/hip_runtime.h>
#include <math.h>

#define LDIM 4096
#define CDIM 1024
#define HDIM 16
#define KDIM 64
#define SDIM 33
#define HALF_SS 16
#define MAXF 16.0f
#define MINF 1.0f
#define MAXR 256.0f

// 0.5-ulp predictors for np's fp32 transcendentals: fp64 op, one round to fp32.
__device__ __forceinline__ float sigmoid_np(float z) {
  float e = (float)exp(-(double)z);
  return __fdiv_rn(1.0f, __fadd_rn(1.0f, e));
}
__device__ __forceinline__ float silu_f(float z) {  // jax.nn order: z * sigmoid(z)
  return __fmul_rn(z, sigmoid_np(z));
}

// numpy pairwise-8 sum (8 <= n <= 128 path)
__device__ __forceinline__ float np_pairwise_sum(const float* a, int n) {
  float r[8];
#pragma unroll
  for (int j = 0; j < 8; ++j) r[j] = a[j];
  int i = 8;
  for (; i + 8 <= n; i += 8)
#pragma unroll
    for (int j = 0; j < 8; ++j) r[j] = __fadd_rn(r[j], a[i + j]);
  float res = __fadd_rn(__fadd_rn(__fadd_rn(r[0], r[1]), __fadd_rn(r[2], r[3])),
                        __fadd_rn(__fadd_rn(r[4], r[5]), __fadd_rn(r[6], r[7])));
  for (; i < n; ++i) res = __fadd_rn(res, a[i]);
  return res;
}

// ------- Kernel A: wave projection — fp64 dot (8-lane split) -> fp32 cast ----
__global__ __launch_bounds__(256) void wave_kernel(
    const float* __restrict__ x, const float* __restrict__ Ww,
    const float* __restrict__ bw, float* __restrict__ fa, float* __restrict__ pa) {
  __shared__ float xs[CDIM];
  __shared__ float wp[2 * HDIM];
  int l = blockIdx.x;
  int tid = threadIdx.x;
  const float* xrow = x + (size_t)l * CDIM;
  for (int c = tid; c < CDIM; c += 256) xs[c] = xrow[c];
  __syncthreads();
  int j = tid >> 3, sub = tid & 7;  // 32 outputs x 8 lanes, fp64 partials
  const float* wrow = Ww + j * CDIM;
  double acc = 0.0;
  for (int c = sub; c < CDIM; c += 8) acc += (double)xs[c] * (double)wrow[c];
  for (int off = 4; off; off >>= 1) acc += __shfl_down(acc, off, 8);
  if (sub == 0) {
    float v32 = (float)(acc + (double)bw[j]);  // single cast to fp32 (bw == 0)
    wp[j] = silu_f(v32);
  }
  __syncthreads();
  if (tid == 0) {
    float fv[HDIM], pv[HDIM];
    for (int h = 0; h < HDIM; ++h) {
      fv[h] = __fadd_rn(__fmul_rn(sigmoid_np(wp[h]), MAXF - MINF), MINF);
      float t32 = (float)tanh((double)wp[HDIM + h]);
      pv[h] = __fmul_rn(t32, MAXF);
    }
    fa[l] = __fdiv_rn(np_pairwise_sum(fv, HDIM), (float)HDIM);
    pa[l] = __fdiv_rn(np_pairwise_sum(pv, HDIM), (float)HDIM);
  }
}

// --- km GEMM: C = silu(fp32(A64 @ B64^T)); 128x64 tile, 8x4 fp64 acc ---------
// fp64 accumulate (np hoists matmul to fp64), fp32 silu/store. UNCHANGED R11.
__global__ __launch_bounds__(256) void gemm_bt_silu_f64(
    const float* __restrict__ A, const float* __restrict__ B,
    const float* __restrict__ bias, float* __restrict__ Cout,
    int M, int N, int Kd) {
  __shared__ float Asf[16][128];
  __shared__ float Bsf[16][64];
  int tid = threadIdx.x;
  int tx = tid & 15, ty = tid >> 4;
  int m0 = blockIdx.y * 128, n0 = blockIdx.x * 64;
  double acc[8][4] = {};
  for (int kt = 0; kt < Kd; kt += 16) {
#pragma unroll
    for (int q = 0; q < 2; ++q) {
      int e = tid + 256 * q;
      int row = e >> 2, kq = (e & 3) * 4;
      float4 va = *(const float4*)(A + (size_t)(m0 + row) * Kd + kt + kq);
      Asf[kq + 0][row] = va.x; Asf[kq + 1][row] = va.y;
      Asf[kq + 2][row] = va.z; Asf[kq + 3][row] = va.w;
    }
    {
      int row = tid >> 2, kq = (tid & 3) * 4;
      float4 vb = *(const float4*)(B + (size_t)(n0 + row) * Kd + kt + kq);
      Bsf[kq + 0][row] = vb.x; Bsf[kq + 1][row] = vb.y;
      Bsf[kq + 2][row] = vb.z; Bsf[kq + 3][row] = vb.w;
    }
    __syncthreads();
#pragma unroll
    for (int kk = 0; kk < 16; ++kk) {
      float4 a0 = *(const float4*)&Asf[kk][ty * 8];
      float4 a1 = *(const float4*)&Asf[kk][ty * 8 + 4];
      float4 b4 = *(const float4*)&Bsf[kk][tx * 4];
      double a[8] = {(double)a0.x, (double)a0.y, (double)a0.z, (double)a0.w,
                     (double)a1.x, (double)a1.y, (double)a1.z, (double)a1.w};
      double b[4] = {(double)b4.x, (double)b4.y, (double)b4.z, (double)b4.w};
#pragma unroll
      for (int i = 0; i < 8; ++i)
#pragma unroll
        for (int j2 = 0; j2 < 4; ++j2) acc[i][j2] += a[i] * b[j2];
    }
    __syncthreads();
  }
#pragma unroll
  for (int i = 0; i < 8; ++i) {
    int mm = m0 + ty * 8 + i;
#pragma unroll
    for (int j2 = 0; j2 < 4; ++j2) {
      int nn = n0 + tx * 4 + j2;
      float v32 = (float)acc[i][j2];
      v32 = __fadd_rn(v32, bias[nn]);
      Cout[(size_t)mm * N + nn] = silu_f(v32);
    }
  }
}

// --- out GEMM: fp32 accumulate (comparison is bf16-granular; margin ~1e4) ----
__global__ __launch_bounds__(256) void gemm_bt_silu_f32(
    const float* __restrict__ A, const float* __restrict__ B,
    float* __restrict__ Cout, int M, int N, int Kd) {
  __shared__ float Asf[16][128];
  __shared__ float Bsf[16][64];
  int tid = threadIdx.x;
  int tx = tid & 15, ty = tid >> 4;
  int m0 = blockIdx.y * 128, n0 = blockIdx.x * 64;
  float acc[8][4] = {};
  for (int kt = 0; kt < Kd; kt += 16) {
#pragma unroll
    for (int q = 0; q < 2; ++q) {
      int e = tid + 256 * q;
      int row = e >> 2, kq = (e & 3) * 4;
      float4 va = *(const float4*)(A + (size_t)(m0 + row) * Kd + kt + kq);
      Asf[kq + 0][row] = va.x; Asf[kq + 1][row] = va.y;
      Asf[kq + 2][row] = va.z; Asf[kq + 3][row] = va.w;
    }
    {
      int row = tid >> 2, kq = (tid & 3) * 4;
      float4 vb = *(const float4*)(B + (size_t)(n0 + row) * Kd + kt + kq);
      Bsf[kq + 0][row] = vb.x; Bsf[kq + 1][row] = vb.y;
      Bsf[kq + 2][row] = vb.z; Bsf[kq + 3][row] = vb.w;
    }
    __syncthreads();
#pragma unroll
    for (int kk = 0; kk < 16; ++kk) {
      float4 a0 = *(const float4*)&Asf[kk][ty * 8];
      float4 a1 = *(const float4*)&Asf[kk][ty * 8 + 4];
      float4 b4 = *(const float4*)&Bsf[kk][tx * 4];
      float a[8] = {a0.x, a0.y, a0.z, a0.w, a1.x, a1.y, a1.z, a1.w};
      float b[4] = {b4.x, b4.y, b4.z, b4.w};
#pragma unroll
      for (int i = 0; i < 8; ++i)
#pragma unroll
        for (int j2 = 0; j2 < 4; ++j2) acc[i][j2] += a[i] * b[j2];  // fp32 fmac
    }
    __syncthreads();
  }
#pragma unroll
  for (int i = 0; i < 8; ++i) {
    int mm = m0 + ty * 8 + i;
#pragma unroll
    for (int j2 = 0; j2 < 4; ++j2) {
      int nn = n0 + tx * 4 + j2;
      Cout[(size_t)mm * N + nn] = silu_f(acc[i][j2]);
    }
  }
}

// ---------------- Kernel C: fp32 chain — byte-identical to R10/R11 -----------
__global__ __launch_bounds__(256) void conv_kernel(
    const float* __restrict__ x, const float* __restrict__ km,
    const float* __restrict__ fa, const float* __restrict__ pa,
    float* __restrict__ conv) {
  int l = blockIdx.x;
  int tid = threadIdx.x;
  __shared__ int s_idx[SDIM];
  __shared__ int s_ifl[SDIM];
  __shared__ float s_wc[SDIM];
  __shared__ float s_val[SDIM];
  __shared__ float kern[HDIM][SDIM];
  __shared__ float s_den[HDIM];
  if (tid < SDIM) {
    float f = fa[l], p = pa[l];
    float rel = __fadd_rn(__fmul_rn((float)(tid - HALF_SS), f), p);
    float pos = __fadd_rn((float)l, rel);
    bool valid = (pos >= 0.f) && (pos < (float)LDIM);
    int idx = (int)pos;                       // trunc toward zero
    idx = min(max(idx, 0), LDIM - 1);
    s_idx[tid] = idx;
    s_val[tid] = valid ? 1.f : 0.f;
    float np_ = __fdiv_rn(__fadd_rn(rel, MAXR), 2.f * MAXR);
    np_ = fminf(fmaxf(np_, 0.f), 1.f);
    float idxf = __fmul_rn(np_, (float)(KDIM - 1));
    int ifl = (int)idxf;
    ifl = min(max(ifl, 0), KDIM - 2);
    s_ifl[tid] = ifl;
    s_wc[tid] = __fsub_rn(idxf, (float)ifl);
  }
  __syncthreads();
  for (int t = tid; t < HDIM * SDIM; t += 256) {
    int h = t / SDIM, s = t - h * SDIM;
    const float* kb = km + (size_t)l * CDIM + h * KDIM;
    float wc = s_wc[s];
    float wf = __fsub_rn(1.f, wc);
    float v = __fadd_rn(__fmul_rn(kb[s_ifl[s]], wf), __fmul_rn(kb[s_ifl[s] + 1], wc));
    kern[h][s] = __fmul_rn(v, s_val[s]);
  }
  __syncthreads();
  if (tid < HDIM) {
    float sum = np_pairwise_sum(&kern[tid][0], SDIM);
    s_den[tid] = __fadd_rn(sum, 1e-8f);
  }
  __syncthreads();
  for (int t = tid; t < HDIM * SDIM; t += 256) {
    int h = t / SDIM, s = t - h * SDIM;
    kern[h][s] = __fdiv_rn(kern[h][s], s_den[h]);
  }
  __syncthreads();
  float acc[4] = {0.f, 0.f, 0.f, 0.f};
  for (int s = 0; s < SDIM; ++s) {
    const float* xr = x + (size_t)s_idx[s] * CDIM;
#pragma unroll
    for (int q = 0; q < 4; ++q) {
      int c = tid + q * 256;
      acc[q] = __fadd_rn(acc[q], __fmul_rn(xr[c], kern[c >> 6][s]));
    }
  }
#pragma unroll
  for (int q = 0; q < 4; ++q) {
    int c = tid + q * 256;
    conv[(size_t)l * CDIM + c] = acc[q];
  }
}

extern "C" void kernel_launch(void* const* d_in, const int* in_sizes, int n_in,
                              void* d_out, int out_size, void* d_ws, size_t ws_size,
                              hipStream_t stream) {
  const float* x  = (const float*)d_in[0];
  const float* Ww = (const float*)d_in[1];
  const float* bw = (const float*)d_in[2];
  const float* Wk = (const float*)d_in[3];
  const float* bk = (const float*)d_in[4];
  const float* Wo = (const float*)d_in[5];
  float* out = (float*)d_out;

  float* fa   = (float*)d_ws;
  float* pa   = fa + LDIM;
  float* km   = pa + LDIM;                   // 16 MB
  float* conv = km + (size_t)LDIM * CDIM;    // 16 MB

  wave_kernel<<<LDIM, 256, 0, stream>>>(x, Ww, bw, fa, pa);

  dim3 ggrid(CDIM / 64, LDIM / 128);
  gemm_bt_silu_f64<<<ggrid, 256, 0, stream>>>(x, Wk, bk, km, LDIM, CDIM, CDIM);

  conv_kernel<<<LDIM, 256, 0, stream>>>(x, km, fa, pa, conv);

  gemm_bt_silu_f32<<<ggrid, 256, 0, stream>>>(conv, Wo, out, LDIM, CDIM, CDIM);
}

// Round 14
// 520.219 us; speedup vs baseline: 1.2696x; 1.0376x over previous
//
#include <hip/hip_runtime.h>
#include <math.h>

#define LDIM 4096
#define CDIM 1024
#define HDIM 16
#define KDIM 64
#define SDIM 33
#define HALF_SS 16
#define MAXF 16.0f
#define MINF 1.0f
#define MAXR 256.0f

// 0.5-ulp predictors for np's fp32 transcendentals: fp64 op, one round to fp32.
__device__ __forceinline__ float sigmoid_np(float z) {
  float e = (float)exp(-(double)z);
  return __fdiv_rn(1.0f, __fadd_rn(1.0f, e));
}
__device__ __forceinline__ float silu_f(float z) {  // jax.nn order: z * sigmoid(z)
  return __fmul_rn(z, sigmoid_np(z));
}

// numpy pairwise-8 sum (8 <= n <= 128 path)
__device__ __forceinline__ float np_pairwise_sum(const float* a, int n) {
  float r[8];
#pragma unroll
  for (int j = 0; j < 8; ++j) r[j] = a[j];
  int i = 8;
  for (; i + 8 <= n; i += 8)
#pragma unroll
    for (int j = 0; j < 8; ++j) r[j] = __fadd_rn(r[j], a[i + j]);
  float res = __fadd_rn(__fadd_rn(__fadd_rn(r[0], r[1]), __fadd_rn(r[2], r[3])),
                        __fadd_rn(__fadd_rn(r[4], r[5]), __fadd_rn(r[6], r[7])));
  for (; i < n; ++i) res = __fadd_rn(res, a[i]);
  return res;
}

// ------- Kernel A: wave projection — fp64 dot (8-lane split) -> fp32 cast ----
__global__ __launch_bounds__(256) void wave_kernel(
    const float* __restrict__ x, const float* __restrict__ Ww,
    const float* __restrict__ bw, float* __restrict__ fa, float* __restrict__ pa) {
  __shared__ float xs[CDIM];
  __shared__ float wp[2 * HDIM];
  int l = blockIdx.x;
  int tid = threadIdx.x;
  const float* xrow = x + (size_t)l * CDIM;
  for (int c = tid; c < CDIM; c += 256) xs[c] = xrow[c];
  __syncthreads();
  int j = tid >> 3, sub = tid & 7;  // 32 outputs x 8 lanes, fp64 partials
  const float* wrow = Ww + j * CDIM;
  double acc = 0.0;
  for (int c = sub; c < CDIM; c += 8) acc += (double)xs[c] * (double)wrow[c];
  for (int off = 4; off; off >>= 1) acc += __shfl_down(acc, off, 8);
  if (sub == 0) {
    float v32 = (float)(acc + (double)bw[j]);  // single cast to fp32 (bw == 0)
    wp[j] = silu_f(v32);
  }
  __syncthreads();
  if (tid == 0) {
    float fv[HDIM], pv[HDIM];
    for (int h = 0; h < HDIM; ++h) {
      fv[h] = __fadd_rn(__fmul_rn(sigmoid_np(wp[h]), MAXF - MINF), MINF);
      float t32 = (float)tanh((double)wp[HDIM + h]);
      pv[h] = __fmul_rn(t32, MAXF);
    }
    fa[l] = __fdiv_rn(np_pairwise_sum(fv, HDIM), (float)HDIM);
    pa[l] = __fdiv_rn(np_pairwise_sum(pv, HDIM), (float)HDIM);
  }
}

// --- km GEMM: C = silu(fp32(A64 @ B64^T) + bias); 128x64 tile, 8x4 fp64 acc --
// LDS staged as double (cvt once at staging); inner loop pure v_fma_f64.
// Arithmetic bit-identical to R12: same products, same k-ascending chains.
__global__ __launch_bounds__(256) void gemm_bt_silu_f64(
    const float* __restrict__ A, const float* __restrict__ B,
    const float* __restrict__ bias, float* __restrict__ Cout,
    int M, int N, int Kd) {
  __shared__ double Asd[16][128];  // 16 KB
  __shared__ double Bsd[16][64];   // 8 KB
  int tid = threadIdx.x;
  int tx = tid & 15, ty = tid >> 4;
  int m0 = blockIdx.y * 128, n0 = blockIdx.x * 64;
  double acc[8][4] = {};
  for (int kt = 0; kt < Kd; kt += 16) {
    // stage A: 128 rows x 16 k; 2 float4 per thread, cvt to double once
#pragma unroll
    for (int q = 0; q < 2; ++q) {
      int e = tid + 256 * q;
      int row = e >> 2, kq = (e & 3) * 4;
      float4 va = *(const float4*)(A + (size_t)(m0 + row) * Kd + kt + kq);
      Asd[kq + 0][row] = (double)va.x; Asd[kq + 1][row] = (double)va.y;
      Asd[kq + 2][row] = (double)va.z; Asd[kq + 3][row] = (double)va.w;
    }
    // stage B: 64 rows x 16 k; 1 float4 per thread
    {
      int row = tid >> 2, kq = (tid & 3) * 4;
      float4 vb = *(const float4*)(B + (size_t)(n0 + row) * Kd + kt + kq);
      Bsd[kq + 0][row] = (double)vb.x; Bsd[kq + 1][row] = (double)vb.y;
      Bsd[kq + 2][row] = (double)vb.z; Bsd[kq + 3][row] = (double)vb.w;
    }
    __syncthreads();
#pragma unroll
    for (int kk = 0; kk < 16; ++kk) {
      double a[8], b[4];
#pragma unroll
      for (int i = 0; i < 8; ++i) a[i] = Asd[kk][ty * 8 + i];
#pragma unroll
      for (int j2 = 0; j2 < 4; ++j2) b[j2] = Bsd[kk][tx * 4 + j2];
#pragma unroll
      for (int i = 0; i < 8; ++i)
#pragma unroll
        for (int j2 = 0; j2 < 4; ++j2) acc[i][j2] += a[i] * b[j2];  // v_fma_f64
    }
    __syncthreads();
  }
#pragma unroll
  for (int i = 0; i < 8; ++i) {
    int mm = m0 + ty * 8 + i;
#pragma unroll
    for (int j2 = 0; j2 < 4; ++j2) {
      int nn = n0 + tx * 4 + j2;
      float v32 = (float)acc[i][j2];     // fp64 dot -> one fp32 cast
      v32 = __fadd_rn(v32, bias[nn]);    // bias == 0
      Cout[(size_t)mm * N + nn] = silu_f(v32);
    }
  }
}

// --- out GEMM: fp32 accumulate; 128x128 tile, 8x8 acc/thread ----------------
// Per-element k-order identical to R12 (sequential fmac chain) -> same bits.
__global__ __launch_bounds__(256) void gemm_bt_silu_f32(
    const float* __restrict__ A, const float* __restrict__ B,
    float* __restrict__ Cout, int M, int N, int Kd) {
  __shared__ float Asf[16][128];
  __shared__ float Bsf[16][128];
  int tid = threadIdx.x;
  int tx = tid & 15, ty = tid >> 4;
  int m0 = blockIdx.y * 128, n0 = blockIdx.x * 128;
  float acc[8][8] = {};
  for (int kt = 0; kt < Kd; kt += 16) {
#pragma unroll
    for (int q = 0; q < 2; ++q) {
      int e = tid + 256 * q;
      int row = e >> 2, kq = (e & 3) * 4;
      float4 va = *(const float4*)(A + (size_t)(m0 + row) * Kd + kt + kq);
      Asf[kq + 0][row] = va.x; Asf[kq + 1][row] = va.y;
      Asf[kq + 2][row] = va.z; Asf[kq + 3][row] = va.w;
      float4 vb = *(const float4*)(B + (size_t)(n0 + row) * Kd + kt + kq);
      Bsf[kq + 0][row] = vb.x; Bsf[kq + 1][row] = vb.y;
      Bsf[kq + 2][row] = vb.z; Bsf[kq + 3][row] = vb.w;
    }
    __syncthreads();
#pragma unroll
    for (int kk = 0; kk < 16; ++kk) {
      float4 a0 = *(const float4*)&Asf[kk][ty * 8];
      float4 a1 = *(const float4*)&Asf[kk][ty * 8 + 4];
      float4 b0 = *(const float4*)&Bsf[kk][tx * 8];
      float4 b1 = *(const float4*)&Bsf[kk][tx * 8 + 4];
      float a[8] = {a0.x, a0.y, a0.z, a0.w, a1.x, a1.y, a1.z, a1.w};
      float b[8] = {b0.x, b0.y, b0.z, b0.w, b1.x, b1.y, b1.z, b1.w};
#pragma unroll
      for (int i = 0; i < 8; ++i)
#pragma unroll
        for (int j2 = 0; j2 < 8; ++j2) acc[i][j2] += a[i] * b[j2];  // fp32 fmac
    }
    __syncthreads();
  }
#pragma unroll
  for (int i = 0; i < 8; ++i) {
    int mm = m0 + ty * 8 + i;
#pragma unroll
    for (int j2 = 0; j2 < 8; ++j2) {
      int nn = n0 + tx * 8 + j2;
      Cout[(size_t)mm * N + nn] = silu_f(acc[i][j2]);
    }
  }
}

// ---------------- Kernel C: fp32 chain — byte-identical to R10..R12 ----------
__global__ __launch_bounds__(256) void conv_kernel(
    const float* __restrict__ x, const float* __restrict__ km,
    const float* __restrict__ fa, const float* __restrict__ pa,
    float* __restrict__ conv) {
  int l = blockIdx.x;
  int tid = threadIdx.x;
  __shared__ int s_idx[SDIM];
  __shared__ int s_ifl[SDIM];
  __shared__ float s_wc[SDIM];
  __shared__ float s_val[SDIM];
  __shared__ float kern[HDIM][SDIM];
  __shared__ float s_den[HDIM];
  if (tid < SDIM) {
    float f = fa[l], p = pa[l];
    float rel = __fadd_rn(__fmul_rn((float)(tid - HALF_SS), f), p);
    float pos = __fadd_rn((float)l, rel);
    bool valid = (pos >= 0.f) && (pos < (float)LDIM);
    int idx = (int)pos;                       // trunc toward zero
    idx = min(max(idx, 0), LDIM - 1);
    s_idx[tid] = idx;
    s_val[tid] = valid ? 1.f : 0.f;
    float np_ = __fdiv_rn(__fadd_rn(rel, MAXR), 2.f * MAXR);
    np_ = fminf(fmaxf(np_, 0.f), 1.f);
    float idxf = __fmul_rn(np_, (float)(KDIM - 1));
    int ifl = (int)idxf;
    ifl = min(max(ifl, 0), KDIM - 2);
    s_ifl[tid] = ifl;
    s_wc[tid] = __fsub_rn(idxf, (float)ifl);
  }
  __syncthreads();
  for (int t = tid; t < HDIM * SDIM; t += 256) {
    int h = t / SDIM, s = t - h * SDIM;
    const float* kb = km + (size_t)l * CDIM + h * KDIM;
    float wc = s_wc[s];
    float wf = __fsub_rn(1.f, wc);
    float v = __fadd_rn(__fmul_rn(kb[s_ifl[s]], wf), __fmul_rn(kb[s_ifl[s] + 1], wc));
    kern[h][s] = __fmul_rn(v, s_val[s]);
  }
  __syncthreads();
  if (tid < HDIM) {
    float sum = np_pairwise_sum(&kern[tid][0], SDIM);
    s_den[tid] = __fadd_rn(sum, 1e-8f);
  }
  __syncthreads();
  for (int t = tid; t < HDIM * SDIM; t += 256) {
    int h = t / SDIM, s = t - h * SDIM;
    kern[h][s] = __fdiv_rn(kern[h][s], s_den[h]);
  }
  __syncthreads();
  float acc[4] = {0.f, 0.f, 0.f, 0.f};
  for (int s = 0; s < SDIM; ++s) {
    const float* xr = x + (size_t)s_idx[s] * CDIM;
#pragma unroll
    for (int q = 0; q < 4; ++q) {
      int c = tid + q * 256;
      acc[q] = __fadd_rn(acc[q], __fmul_rn(xr[c], kern[c >> 6][s]));
    }
  }
#pragma unroll
  for (int q = 0; q < 4; ++q) {
    int c = tid + q * 256;
    conv[(size_t)l * CDIM + c] = acc[q];
  }
}

extern "C" void kernel_launch(void* const* d_in, const int* in_sizes, int n_in,
                              void* d_out, int out_size, void* d_ws, size_t ws_size,
                              hipStream_t stream) {
  const float* x  = (const float*)d_in[0];
  const float* Ww = (const float*)d_in[1];
  const float* bw = (const float*)d_in[2];
  const float* Wk = (const float*)d_in[3];
  const float* bk = (const float*)d_in[4];
  const float* Wo = (const float*)d_in[5];
  float* out = (float*)d_out;

  float* fa   = (float*)d_ws;
  float* pa   = fa + LDIM;
  float* km   = pa + LDIM;                   // 16 MB
  float* conv = km + (size_t)LDIM * CDIM;    // 16 MB

  wave_kernel<<<LDIM, 256, 0, stream>>>(x, Ww, bw, fa, pa);

  dim3 kmgrid(CDIM / 64, LDIM / 128);        // 16 x 32 = 512 blocks
  gemm_bt_silu_f64<<<kmgrid, 256, 0, stream>>>(x, Wk, bk, km, LDIM, CDIM, CDIM);

  conv_kernel<<<LDIM, 256, 0, stream>>>(x, km, fa, pa, conv);

  dim3 ogrid(CDIM / 128, LDIM / 128);        // 8 x 32 = 256 blocks
  gemm_bt_silu_f32<<<ogrid, 256, 0, stream>>>(conv, Wo, out, LDIM, CDIM, CDIM);
}